// Round 1
// baseline (278.592 us; speedup 1.0000x reference)
//
#include <hip/hip_runtime.h>

// EuclideanFastAttention — MI355X (gfx950)
// Route: A = (1/6) * qr · kr^T per batch (256x256, K=6912), out = A · v.
// 14.5 + 2.4 + 3.6 GFLOP total vs ~130 GFLOP for the reference kv route.

typedef unsigned short u16;
typedef __attribute__((ext_vector_type(8))) short short8;   // 8 x bf16 bits (MFMA frag)
typedef __attribute__((ext_vector_type(4))) float f32x4;    // MFMA acc
typedef __attribute__((ext_vector_type(4))) unsigned short u16x4;

static constexpr int N_NODES = 4096;
static constexpr int NBATCH  = 16;
static constexpr int NB      = 256;      // nodes per batch
static constexpr int NDEG    = 9;
static constexpr int FDIM    = 128;
static constexpr int MD      = NDEG * FDIM;   // 1152
static constexpr int G       = 6;
static constexpr int KTOT    = G * MD;        // 6912

// ws layout (bytes)
static constexpr size_t OFF_COS = 0;                            // N*384 f32
static constexpr size_t OFF_SIN = OFF_COS + (size_t)N_NODES*384*4;
static constexpr size_t OFF_WT  = OFF_SIN + (size_t)N_NODES*384*4;   // 9 * 128*128 bf16 [mat*3+l][j][f]
static constexpr size_t OFF_QR  = OFF_WT  + (size_t)9*128*128*2;     // N*6912 bf16
static constexpr size_t OFF_KR  = OFF_QR  + (size_t)N_NODES*KTOT*2;
static constexpr size_t OFF_VBF = OFF_KR  + (size_t)N_NODES*KTOT*2;  // N*1152 bf16 [n][d]
static constexpr size_t OFF_VT  = OFF_VBF + (size_t)N_NODES*MD*2;    // [d][n] bf16
static constexpr size_t OFF_A   = OFF_VT  + (size_t)N_NODES*MD*2;    // B*256*256 f32
// total ~149.2 MB

__device__ inline u16 f2bf(float x) {
    union { float f; unsigned u; } v; v.f = x;
    unsigned r = v.u + 0x7fffu + ((v.u >> 16) & 1u);   // RNE
    return (u16)(r >> 16);
}

// ---------------- kernel 1: sincos table -------------------------------------
// cos/sin[n][g][i], g in 0..5 (+x,-x,+y,-y,+z,-z), i in 0..63
__global__ __launch_bounds__(256) void k_trig(const float* __restrict__ pos,
                                              float* __restrict__ cosb,
                                              float* __restrict__ sinb) {
    int idx = blockIdx.x * 256 + threadIdx.x;          // N*384 exactly
    if (idx >= N_NODES * 384) return;
    int n = idx / 384, r = idx % 384;
    int g = r >> 6, i = r & 63;
    float p = pos[n * 3 + (g >> 1)];
    float sgn = (g & 1) ? -1.0f : 1.0f;
    float theta = (float)i * (8.0f / (63.0f * 10.0f)); // linspace(0,8,64)/10
    float ang = sgn * p * theta;
    float s, c;
    sincosf(ang, &s, &c);
    cosb[idx] = c;
    sinb[idx] = s;
}

// ---------------- kernel 2: W transpose + bf16 cast --------------------------
// wt[(mat*3+l)][j][f] = W_mat[l][f][j]
__global__ __launch_bounds__(256) void k_wtrans(const float* __restrict__ Wq,
                                                const float* __restrict__ Wk,
                                                const float* __restrict__ Wv,
                                                u16* __restrict__ wt) {
    int blk = blockIdx.x;                  // 0..8
    int mat = blk / 3, l = blk % 3;
    const float* W = (mat == 0 ? Wq : (mat == 1 ? Wk : Wv)) + (size_t)l * 128 * 128;
    u16* dst = wt + (size_t)blk * 128 * 128;
    for (int e = threadIdx.x; e < 128 * 128; e += 256) {
        int j = e >> 7, f = e & 127;
        dst[e] = f2bf(W[f * 128 + j]);
    }
}

// ---------------- kernel 3: dense(q/k/v) + bias + RoPE -----------------------
// grid (64 node-tiles, 9 m, 3 mats). Y = X_m * W  (64x128, K=128), then:
//   mat 0/1: write qr/kr bf16 for all 6 g;  mat 2: write v bf16.
__global__ __launch_bounds__(256) void k_qkv(const float* __restrict__ X,
                                             const u16* __restrict__ wt,
                                             const float* __restrict__ bq,
                                             const float* __restrict__ bk,
                                             const float* __restrict__ bv,
                                             const float* __restrict__ cosb,
                                             const float* __restrict__ sinb,
                                             u16* __restrict__ qr,
                                             u16* __restrict__ kr,
                                             u16* __restrict__ vbf) {
    const int nt = blockIdx.x, m = blockIdx.y, mat = blockIdx.z;
    const int n0 = nt * 64;
    const int deg = (m == 0) ? 0 : (m < 4 ? 1 : 2);
    const int tid = threadIdx.x;

    __shared__ u16 Xs[64 * 136];    // 64 nodes x 128 f, pad 8 (bank-shift 4/row)
    __shared__ u16 Ws[128 * 136];   // 128 j x 128 f

    // stage X (fp32 -> bf16)
    for (int e = tid; e < 64 * 32; e += 256) {
        int r = e >> 5, f4 = e & 31;
        float4 xv = *(const float4*)(X + (size_t)(n0 + r) * MD + m * 128 + f4 * 4);
        u16x4 o; o.x = f2bf(xv.x); o.y = f2bf(xv.y); o.z = f2bf(xv.z); o.w = f2bf(xv.w);
        *(u16x4*)(Xs + r * 136 + f4 * 4) = o;
    }
    // stage W (already bf16): rows j, contiguous f
    {
        const uint4* wsrc = (const uint4*)(wt + (size_t)(mat * 3 + deg) * 128 * 128);
        for (int e = tid; e < 128 * 16; e += 256) {
            int j = e >> 4, f8 = e & 15;
            *(uint4*)(Ws + j * 136 + f8 * 8) = wsrc[j * 16 + f8];
        }
    }
    __syncthreads();

    const int w = tid >> 6, lane = tid & 63, quad = lane >> 4, lrow = lane & 15;
    f32x4 acc[8];
#pragma unroll
    for (int ct = 0; ct < 8; ct++) acc[ct] = (f32x4){0.f, 0.f, 0.f, 0.f};

#pragma unroll
    for (int ks = 0; ks < 4; ks++) {
        short8 a = *(const short8*)(Xs + (w * 16 + lrow) * 136 + ks * 32 + quad * 8);
#pragma unroll
        for (int ct = 0; ct < 8; ct++) {
            short8 bfr = *(const short8*)(Ws + (ct * 16 + lrow) * 136 + ks * 32 + quad * 8);
            acc[ct] = __builtin_amdgcn_mfma_f32_16x16x32_bf16(a, bfr, acc[ct], 0, 0, 0);
        }
    }

    const float* bias = (mat == 0) ? bq : ((mat == 1) ? bk : bv);
    u16* dst = (mat == 0) ? qr : kr;

#pragma unroll
    for (int ct = 0; ct < 8; ct++) {
        int j = ct * 16 + lrow;
        float bj = (m == 0) ? bias[j] : 0.0f;
#pragma unroll
        for (int r = 0; r < 4; r++) {
            int node = n0 + w * 16 + quad * 4 + r;   // C-layout: row=quad*4+reg, col=lane&15
            float y = acc[ct][r] + bj;
            if (mat == 2) {
                vbf[(size_t)node * MD + m * 128 + j] = f2bf(y);
            } else {
                float p = __shfl_xor(y, 1);          // partner feature (j^1), same row
                int i = j >> 1;
                int cb = node * 384;
#pragma unroll
                for (int gp = 0; gp < 3; gp++) {     // g pairs (+dir, -dir): cos same, sin negated
                    float c = cosb[cb + gp * 128 + i];
                    float s = sinb[cb + gp * 128 + i];
                    float t1 = y * c, t2 = p * s;
                    float r0, r1;
                    if ((j & 1) == 0) { r0 = t1 - t2; r1 = t1 + t2; }
                    else             { r0 = t1 + t2; r1 = t1 - t2; }
                    size_t o = (size_t)node * KTOT + (size_t)(gp * 2) * MD + m * 128 + j;
                    dst[o]      = f2bf(r0);
                    dst[o + MD] = f2bf(r1);
                }
            }
        }
    }
}

// ---------------- kernel 4: transpose v -> vt[d][n] --------------------------
__global__ __launch_bounds__(256) void k_transv(const u16* __restrict__ vbf,
                                                u16* __restrict__ vt) {
    int nt = blockIdx.x, dt = blockIdx.y;     // 64 x 18
    __shared__ u16 tile[64 * 65];
    int tid = threadIdx.x;
    for (int e = tid; e < 4096; e += 256) {
        int r = e >> 6, c = e & 63;
        tile[r * 65 + c] = vbf[(size_t)(nt * 64 + r) * MD + dt * 64 + c];
    }
    __syncthreads();
    for (int e = tid; e < 4096; e += 256) {
        int r = e >> 6, c = e & 63;
        vt[(size_t)(dt * 64 + r) * N_NODES + nt * 64 + c] = tile[c * 65 + r];
    }
}

// ---------------- kernel 5: A = (1/6) qr · kr^T per batch --------------------
// 256 blocks: batch (16) x 4x4 tiles of 64x64.  K = 6912, BK = 64.
__global__ __launch_bounds__(256) void k_gemm1(const u16* __restrict__ qr,
                                               const u16* __restrict__ kr,
                                               float* __restrict__ A) {
    int bx = blockIdx.x;
    int b = bx >> 4, t = bx & 15, tr = t >> 2, tc = t & 3;
    int qn0 = b * NB + tr * 64, kn0 = b * NB + tc * 64;
    int tid = threadIdx.x;
    __shared__ u16 Qs[64 * 72];
    __shared__ u16 Ks[64 * 72];
    int w = tid >> 6, lane = tid & 63, quad = lane >> 4, lrow = lane & 15;

    f32x4 acc[4];
#pragma unroll
    for (int ct = 0; ct < 4; ct++) acc[ct] = (f32x4){0.f, 0.f, 0.f, 0.f};

    for (int kc = 0; kc < KTOT / 64; kc++) {
        int k0 = kc * 64;
#pragma unroll
        for (int e = tid; e < 512; e += 256) {
            int r = e >> 3, s = e & 7;
            *(uint4*)(Qs + r * 72 + s * 8) = *(const uint4*)(qr + (size_t)(qn0 + r) * KTOT + k0 + s * 8);
            *(uint4*)(Ks + r * 72 + s * 8) = *(const uint4*)(kr + (size_t)(kn0 + r) * KTOT + k0 + s * 8);
        }
        __syncthreads();
#pragma unroll
        for (int ks = 0; ks < 2; ks++) {
            short8 a = *(const short8*)(Qs + (w * 16 + lrow) * 72 + ks * 32 + quad * 8);
#pragma unroll
            for (int ct = 0; ct < 4; ct++) {
                short8 bfr = *(const short8*)(Ks + (ct * 16 + lrow) * 72 + ks * 32 + quad * 8);
                acc[ct] = __builtin_amdgcn_mfma_f32_16x16x32_bf16(a, bfr, acc[ct], 0, 0, 0);
            }
        }
        __syncthreads();
    }
    const float sc = 1.0f / 6.0f;
#pragma unroll
    for (int ct = 0; ct < 4; ct++)
#pragma unroll
        for (int r = 0; r < 4; r++) {
            int rib = tr * 64 + w * 16 + quad * 4 + r;
            int cib = tc * 64 + ct * 16 + lrow;
            A[(size_t)b * NB * NB + (size_t)rib * NB + cib] = acc[ct][r] * sc;
        }
}

// ---------------- kernel 6: out = A · v per batch (+mask) --------------------
// grid (4 row-tiles, 9 d-tiles of 128, 16 batches).  K = 256, BK = 64.
__global__ __launch_bounds__(256) void k_gemm2(const float* __restrict__ A,
                                               const u16* __restrict__ vt,
                                               const int* __restrict__ gmask,
                                               float* __restrict__ out) {
    int rt = blockIdx.x, dcb = blockIdx.y, b = blockIdx.z;
    int d0 = dcb * 128;
    int tid = threadIdx.x;
    __shared__ u16 As[64 * 72];
    __shared__ u16 Vs[128 * 72];
    int w = tid >> 6, lane = tid & 63, quad = lane >> 4, lrow = lane & 15;

    f32x4 acc[8];
#pragma unroll
    for (int ct = 0; ct < 8; ct++) acc[ct] = (f32x4){0.f, 0.f, 0.f, 0.f};

    for (int kc = 0; kc < 4; kc++) {
        int k0 = kc * 64;
#pragma unroll
        for (int e = tid; e < 1024; e += 256) {    // A fp32 -> bf16
            int r = e >> 4, s = e & 15;
            float4 av = *(const float4*)(A + (size_t)b * NB * NB + (size_t)(rt * 64 + r) * NB + k0 + s * 4);
            u16x4 o; o.x = f2bf(av.x); o.y = f2bf(av.y); o.z = f2bf(av.z); o.w = f2bf(av.w);
            *(u16x4*)(As + r * 72 + s * 4) = o;
        }
#pragma unroll
        for (int e = tid; e < 1024; e += 256) {    // vt rows (d), contiguous k
            int rr = e >> 3, s = e & 7;
            *(uint4*)(Vs + rr * 72 + s * 8) =
                *(const uint4*)(vt + (size_t)(d0 + rr) * N_NODES + b * NB + k0 + s * 8);
        }
        __syncthreads();
#pragma unroll
        for (int ks = 0; ks < 2; ks++) {
            short8 a = *(const short8*)(As + (w * 16 + lrow) * 72 + ks * 32 + quad * 8);
#pragma unroll
            for (int ct = 0; ct < 8; ct++) {
                short8 bfr = *(const short8*)(Vs + (ct * 16 + lrow) * 72 + ks * 32 + quad * 8);
                acc[ct] = __builtin_amdgcn_mfma_f32_16x16x32_bf16(a, bfr, acc[ct], 0, 0, 0);
            }
        }
        __syncthreads();
    }
    int mv = gmask[b];   // robust for both int32 and byte-bool all-ones layouts
#pragma unroll
    for (int ct = 0; ct < 8; ct++)
#pragma unroll
        for (int r = 0; r < 4; r++) {
            int node = b * NB + rt * 64 + w * 16 + quad * 4 + r;
            int d = d0 + ct * 16 + lrow;
            out[(size_t)node * MD + d] = mv ? acc[ct][r] : 0.0f;
        }
}

// ---------------- launch -----------------------------------------------------
extern "C" void kernel_launch(void* const* d_in, const int* in_sizes, int n_in,
                              void* d_out, int out_size, void* d_ws, size_t ws_size,
                              hipStream_t stream) {
    (void)in_sizes; (void)n_in; (void)out_size; (void)ws_size;

    const float* X    = (const float*)d_in[0];
    const float* pos  = (const float*)d_in[1];
    const int*   gmask= (const int*)  d_in[3];
    const float* Wq   = (const float*)d_in[4];
    const float* bq   = (const float*)d_in[5];
    const float* Wk   = (const float*)d_in[6];
    const float* bk   = (const float*)d_in[7];
    const float* Wv   = (const float*)d_in[8];
    const float* bv   = (const float*)d_in[9];
    float* out = (float*)d_out;

    char* ws = (char*)d_ws;
    float* cosb = (float*)(ws + OFF_COS);
    float* sinb = (float*)(ws + OFF_SIN);
    u16*   wt   = (u16*)  (ws + OFF_WT);
    u16*   qrp  = (u16*)  (ws + OFF_QR);
    u16*   krp  = (u16*)  (ws + OFF_KR);
    u16*   vbfp = (u16*)  (ws + OFF_VBF);
    u16*   vtp  = (u16*)  (ws + OFF_VT);
    float* Ap   = (float*)(ws + OFF_A);

    k_trig  <<<dim3((N_NODES * 384) / 256), dim3(256), 0, stream>>>(pos, cosb, sinb);
    k_wtrans<<<dim3(9),                     dim3(256), 0, stream>>>(Wq, Wk, Wv, wt);
    k_qkv   <<<dim3(64, 9, 3),              dim3(256), 0, stream>>>(X, wt, bq, bk, bv,
                                                                    cosb, sinb, qrp, krp, vbfp);
    k_transv<<<dim3(64, 18),                dim3(256), 0, stream>>>(vbfp, vtp);
    k_gemm1 <<<dim3(256),                   dim3(256), 0, stream>>>(qrp, krp, Ap);
    k_gemm2 <<<dim3(4, 9, 16),              dim3(256), 0, stream>>>(Ap, vtp, gmask, out);
}

// Round 2
// 206.629 us; speedup vs baseline: 1.3483x; 1.3483x over previous
//
#include <hip/hip_runtime.h>

// EuclideanFastAttention — MI355X (gfx950)
// Route: A = (1/6) * qr · kr^T per batch (256x256, K=6912, split-K by grid dir),
// out = A · v.  ~21 GFLOP total vs ~130 GFLOP reference kv route.

typedef unsigned short u16;
typedef __attribute__((ext_vector_type(8))) short short8;   // 8 x bf16 bits (MFMA frag)
typedef __attribute__((ext_vector_type(4))) float f32x4;    // MFMA acc
typedef __attribute__((ext_vector_type(4))) unsigned short u16x4;

static constexpr int N_NODES = 4096;
static constexpr int NBATCH  = 16;
static constexpr int NB      = 256;      // nodes per batch
static constexpr int NDEG    = 9;
static constexpr int FDIM    = 128;
static constexpr int MD      = NDEG * FDIM;   // 1152
static constexpr int G       = 6;
static constexpr int KTOT    = G * MD;        // 6912

// ws layout (bytes) — aliased by kernel timeline:
//   trig/wt/qkv -> transv -> gemm1 -> reduce -> gemm2
static constexpr size_t OFF_CS  = 0;                                   // 4096*3*64 float2 = 6.29MB
static constexpr size_t OFF_WT  = OFF_CS  + (size_t)N_NODES*3*64*8;    // 9*128*128 bf16
static constexpr size_t OFF_QR  = OFF_WT  + (size_t)9*128*128*2;       // N*6912 bf16 (56.6MB)
static constexpr size_t OFF_KR  = OFF_QR  + (size_t)N_NODES*KTOT*2;    // 56.6MB
static constexpr size_t OFF_VT  = OFF_KR  + (size_t)N_NODES*KTOT*2;    // [d][n] bf16 9.4MB
static constexpr size_t OFF_VBF = OFF_VT  + (size_t)N_NODES*MD*2;      // [n][d] bf16 9.4MB (dead after transv)
static constexpr size_t OFF_AP  = OFF_VBF;                             // 6*16*256*256 bf16 = 12.6MB (overlaps vbf)
static constexpr size_t OFF_ABF = OFF_QR;                              // 16*256*256 bf16 = 2MB (overlaps qr, written post-gemm1)
// high-water: OFF_AP + 12.6MB = 141.9MB  (< 149.2MB proven in R1)

__device__ inline u16 f2bf(float x) {
    union { float f; unsigned u; } v; v.f = x;
    unsigned r = v.u + 0x7fffu + ((v.u >> 16) & 1u);   // RNE
    return (u16)(r >> 16);
}
__device__ inline float bf2f(u16 h) {
    union { unsigned u; float f; } v; v.u = ((unsigned)h) << 16; return v.f;
}

// ---------------- kernel 1: trig table ---------------------------------------
// cs[n][dim][i] = (cos, sin) of pos[n][dim] * theta_i, dim in 0..2, i in 0..63
__global__ __launch_bounds__(256) void k_trig(const float* __restrict__ pos,
                                              float2* __restrict__ cs) {
    int idx = blockIdx.x * 256 + threadIdx.x;          // N*192 exactly
    int n = idx / 192, r = idx % 192;
    int gp = r >> 6, i = r & 63;
    float p = pos[n * 3 + gp];
    float theta = (float)i * (8.0f / (63.0f * 10.0f)); // linspace(0,8,64)/10
    float s, c;
    sincosf(p * theta, &s, &c);
    cs[idx] = make_float2(c, s);
}

// ---------------- kernel 2: W transpose + bf16 cast --------------------------
// wt[(mat*3+l)][j][f] = W_mat[l][f][j];  grid (9, 4): 64x64 tiles
__global__ __launch_bounds__(256) void k_wtrans(const float* __restrict__ Wq,
                                                const float* __restrict__ Wk,
                                                const float* __restrict__ Wv,
                                                u16* __restrict__ wt) {
    int blk = blockIdx.x;                  // 0..8
    int tt  = blockIdx.y;                  // 0..3
    int mat = blk / 3, l = blk % 3;
    const float* W = (mat == 0 ? Wq : (mat == 1 ? Wk : Wv)) + (size_t)l * 16384;
    int j0 = (tt >> 1) * 64, f0 = (tt & 1) * 64;
    __shared__ u16 tile[64 * 72];
    int tid = threadIdx.x;
    for (int e = tid; e < 1024; e += 256) {      // 64 f-rows x 16 float4
        int r = e >> 4, c = e & 15;
        float4 wv = *(const float4*)(W + (size_t)(f0 + r) * 128 + j0 + c * 4);
        tile[(c * 4 + 0) * 72 + r] = f2bf(wv.x);
        tile[(c * 4 + 1) * 72 + r] = f2bf(wv.y);
        tile[(c * 4 + 2) * 72 + r] = f2bf(wv.z);
        tile[(c * 4 + 3) * 72 + r] = f2bf(wv.w);
    }
    __syncthreads();
    u16* dst = wt + (size_t)blk * 16384;
    for (int e = tid; e < 512; e += 256) {       // 64 j-rows x 8 uint4
        int j = e >> 3, c = e & 7;
        *(uint4*)(dst + (size_t)(j0 + j) * 128 + f0 + c * 8) = *(const uint4*)(tile + j * 72 + c * 8);
    }
}

// ---------------- kernel 3: dense(q/k/v) + bias + RoPE -----------------------
// grid (64 node-tiles, 9 m, 3 mats). Y = X_m * W  (64x128, K=128), then:
//   mat 0/1: RoPE for 3 dim-pairs, LDS-staged, coalesced uint4 stores
//   mat 2:   v bf16 via LDS staging
__global__ __launch_bounds__(256) void k_qkv(const float* __restrict__ X,
                                             const u16* __restrict__ wt,
                                             const float* __restrict__ bq,
                                             const float* __restrict__ bk,
                                             const float* __restrict__ bv,
                                             const float2* __restrict__ cs,
                                             u16* __restrict__ qr,
                                             u16* __restrict__ kr,
                                             u16* __restrict__ vbf) {
    const int nt = blockIdx.x, m = blockIdx.y, mat = blockIdx.z;
    const int n0 = nt * 64;
    const int deg = (m == 0) ? 0 : (m < 4 ? 1 : 2);
    const int tid = threadIdx.x;

    __shared__ u16 smem[26112];       // Xs(64x136) ++ Ws(128x136); reused as O0/O1
    u16* Xs = smem;
    u16* Ws = smem + 64 * 136;

    // stage X (fp32 -> bf16)
    for (int e = tid; e < 64 * 32; e += 256) {
        int r = e >> 5, f4 = e & 31;
        float4 xv = *(const float4*)(X + (size_t)(n0 + r) * MD + m * 128 + f4 * 4);
        u16x4 o; o.x = f2bf(xv.x); o.y = f2bf(xv.y); o.z = f2bf(xv.z); o.w = f2bf(xv.w);
        *(u16x4*)(Xs + r * 136 + f4 * 4) = o;
    }
    // stage W (already bf16)
    {
        const uint4* wsrc = (const uint4*)(wt + (size_t)(mat * 3 + deg) * 16384);
        for (int e = tid; e < 128 * 16; e += 256) {
            int j = e >> 4, f8 = e & 15;
            *(uint4*)(Ws + j * 136 + f8 * 8) = wsrc[j * 16 + f8];
        }
    }
    __syncthreads();

    const int w = tid >> 6, lane = tid & 63, quad = lane >> 4, lrow = lane & 15;
    f32x4 acc[8];
#pragma unroll
    for (int ct = 0; ct < 8; ct++) acc[ct] = (f32x4){0.f, 0.f, 0.f, 0.f};

#pragma unroll
    for (int ks = 0; ks < 4; ks++) {
        short8 a = *(const short8*)(Xs + (w * 16 + lrow) * 136 + ks * 32 + quad * 8);
#pragma unroll
        for (int ct = 0; ct < 8; ct++) {
            short8 bfr = *(const short8*)(Ws + (ct * 16 + lrow) * 136 + ks * 32 + quad * 8);
            acc[ct] = __builtin_amdgcn_mfma_f32_16x16x32_bf16(a, bfr, acc[ct], 0, 0, 0);
        }
    }

    const float* bias = (mat == 0) ? bq : ((mat == 1) ? bk : bv);
    float yv[8][4];
#pragma unroll
    for (int ct = 0; ct < 8; ct++) {
        float bj = (m == 0) ? bias[ct * 16 + lrow] : 0.0f;
#pragma unroll
        for (int r = 0; r < 4; r++) yv[ct][r] = acc[ct][r] + bj;
    }

    if (mat == 2) {
        __syncthreads();                 // Xs/Ws reads complete in all waves
#pragma unroll
        for (int ct = 0; ct < 8; ct++)
#pragma unroll
            for (int r = 0; r < 4; r++) {
                int nl = w * 16 + quad * 4 + r;       // C-layout: row=quad*4+reg
                smem[nl * 136 + ct * 16 + lrow] = f2bf(yv[ct][r]);
            }
        __syncthreads();
        for (int e = tid; e < 1024; e += 256) {
            int nl = e >> 4, c = e & 15;
            *(uint4*)(vbf + (size_t)(n0 + nl) * MD + m * 128 + c * 8) =
                *(const uint4*)(smem + nl * 136 + c * 8);
        }
        return;
    }

    float pv[8][4];                       // partner feature j^1 (same C row)
#pragma unroll
    for (int ct = 0; ct < 8; ct++)
#pragma unroll
        for (int r = 0; r < 4; r++) pv[ct][r] = __shfl_xor(yv[ct][r], 1);

    u16* O0 = smem;                       // g = 2*gp   (+dir)
    u16* O1 = smem + 64 * 136;            // g = 2*gp+1 (-dir: cos same, sin negated)
    u16* dst = (mat == 0) ? qr : kr;
    const bool even = !(lrow & 1);

    for (int gp = 0; gp < 3; gp++) {
        __syncthreads();
#pragma unroll
        for (int ct = 0; ct < 8; ct++) {
            int i = ct * 8 + (lrow >> 1);
#pragma unroll
            for (int r = 0; r < 4; r++) {
                int nl = w * 16 + quad * 4 + r;
                float2 c_s = cs[((size_t)(n0 + nl) * 3 + gp) * 64 + i];
                float t1 = yv[ct][r] * c_s.x, t2 = pv[ct][r] * c_s.y;
                float r0, r1;
                if (even) { r0 = t1 - t2; r1 = t1 + t2; }
                else      { r0 = t1 + t2; r1 = t1 - t2; }
                O0[nl * 136 + ct * 16 + lrow] = f2bf(r0);
                O1[nl * 136 + ct * 16 + lrow] = f2bf(r1);
            }
        }
        __syncthreads();
        for (int e = tid; e < 1024; e += 256) {
            int nl = e >> 4, c = e & 15;
            size_t o = (size_t)(n0 + nl) * KTOT + (size_t)(gp * 2) * MD + m * 128 + c * 8;
            *(uint4*)(dst + o)      = *(const uint4*)(O0 + nl * 136 + c * 8);
            *(uint4*)(dst + o + MD) = *(const uint4*)(O1 + nl * 136 + c * 8);
        }
    }
}

// ---------------- kernel 4: transpose v -> vt[d][n] --------------------------
__global__ __launch_bounds__(256) void k_transv(const u16* __restrict__ vbf,
                                                u16* __restrict__ vt) {
    int nt = blockIdx.x, dt = blockIdx.y;     // 64 x 18
    __shared__ u16 tile[64 * 65];
    int tid = threadIdx.x;
    for (int e = tid; e < 4096; e += 256) {
        int r = e >> 6, c = e & 63;
        tile[r * 65 + c] = vbf[(size_t)(nt * 64 + r) * MD + dt * 64 + c];
    }
    __syncthreads();
    for (int e = tid; e < 4096; e += 256) {
        int r = e >> 6, c = e & 63;
        vt[(size_t)(dt * 64 + r) * N_NODES + nt * 64 + c] = tile[c * 65 + r];
    }
}

// ---------------- kernel 5: Apart[g] = qr_g · kr_g^T (split-K) ---------------
// grid (16 tiles, 16 batches, 6 g) = 1536 blocks, K=1152 each, BK=64.
__global__ __launch_bounds__(256) void k_gemm1(const u16* __restrict__ qr,
                                               const u16* __restrict__ kr,
                                               u16* __restrict__ Apart) {
    int t = blockIdx.x, b = blockIdx.y, g = blockIdx.z;
    int tr = t >> 2, tc = t & 3;
    int qn0 = b * NB + tr * 64, kn0 = b * NB + tc * 64;
    const size_t koff = (size_t)g * MD;
    int tid = threadIdx.x;
    __shared__ u16 Qs[64 * 72];
    __shared__ u16 Ks[64 * 72];
    int w = tid >> 6, lane = tid & 63, quad = lane >> 4, lrow = lane & 15;

    f32x4 acc[4];
#pragma unroll
    for (int ct = 0; ct < 4; ct++) acc[ct] = (f32x4){0.f, 0.f, 0.f, 0.f};

    for (int kc = 0; kc < MD / 64; kc++) {     // 18
        int k0 = kc * 64;
#pragma unroll
        for (int e = tid; e < 512; e += 256) {
            int r = e >> 3, s = e & 7;
            *(uint4*)(Qs + r * 72 + s * 8) = *(const uint4*)(qr + (size_t)(qn0 + r) * KTOT + koff + k0 + s * 8);
            *(uint4*)(Ks + r * 72 + s * 8) = *(const uint4*)(kr + (size_t)(kn0 + r) * KTOT + koff + k0 + s * 8);
        }
        __syncthreads();
#pragma unroll
        for (int ks = 0; ks < 2; ks++) {
            short8 a = *(const short8*)(Qs + (w * 16 + lrow) * 72 + ks * 32 + quad * 8);
#pragma unroll
            for (int ct = 0; ct < 4; ct++) {
                short8 bfr = *(const short8*)(Ks + (ct * 16 + lrow) * 72 + ks * 32 + quad * 8);
                acc[ct] = __builtin_amdgcn_mfma_f32_16x16x32_bf16(a, bfr, acc[ct], 0, 0, 0);
            }
        }
        __syncthreads();
    }
    u16* dst = Apart + ((size_t)g * NBATCH + b) * NB * NB;
#pragma unroll
    for (int ct = 0; ct < 4; ct++)
#pragma unroll
        for (int r = 0; r < 4; r++) {
            int rib = tr * 64 + w * 16 + quad * 4 + r;
            int cib = tc * 64 + ct * 16 + lrow;
            dst[(size_t)rib * NB + cib] = f2bf(acc[ct][r]);
        }
}

// ---------------- kernel 5b: A = (1/6) * sum_g Apart[g]  (bf16) --------------
__global__ __launch_bounds__(256) void k_reduceA(const u16* __restrict__ Ap,
                                                 u16* __restrict__ Abf) {
    int idx = blockIdx.x * 256 + threadIdx.x;    // 131072 uint4 chunks
    size_t base = (size_t)idx * 8;
    float s[8];
#pragma unroll
    for (int i = 0; i < 8; i++) s[i] = 0.f;
#pragma unroll
    for (int g = 0; g < 6; g++) {
        uint4 v = *(const uint4*)(Ap + (size_t)g * (NBATCH * NB * NB) + base);
        const unsigned* u = (const unsigned*)&v;
#pragma unroll
        for (int h = 0; h < 4; h++) {
            s[h * 2]     += bf2f((u16)(u[h] & 0xffff));
            s[h * 2 + 1] += bf2f((u16)(u[h] >> 16));
        }
    }
    const float sc = 1.0f / 6.0f;
    u16 o[8];
#pragma unroll
    for (int i = 0; i < 8; i++) o[i] = f2bf(s[i] * sc);
    *(uint4*)(Abf + base) = *(const uint4*)o;
}

// ---------------- kernel 6: out = A · v per batch (+mask) --------------------
// grid (4 row-tiles, 9 d-tiles of 128, 16 batches).  K = 256, BK = 64.
__global__ __launch_bounds__(256) void k_gemm2(const u16* __restrict__ Abf,
                                               const u16* __restrict__ vt,
                                               const int* __restrict__ gmask,
                                               float* __restrict__ out) {
    int rt = blockIdx.x, dcb = blockIdx.y, b = blockIdx.z;
    int d0 = dcb * 128;
    int tid = threadIdx.x;
    __shared__ u16 As[64 * 72];
    __shared__ u16 Vs[128 * 72];
    int w = tid >> 6, lane = tid & 63, quad = lane >> 4, lrow = lane & 15;

    f32x4 acc[8];
#pragma unroll
    for (int ct = 0; ct < 8; ct++) acc[ct] = (f32x4){0.f, 0.f, 0.f, 0.f};

    for (int kc = 0; kc < 4; kc++) {
        int k0 = kc * 64;
#pragma unroll
        for (int e = tid; e < 512; e += 256) {     // A bf16 tile
            int r = e >> 3, s = e & 7;
            *(uint4*)(As + r * 72 + s * 8) =
                *(const uint4*)(Abf + (size_t)b * NB * NB + (size_t)(rt * 64 + r) * NB + k0 + s * 8);
        }
#pragma unroll
        for (int e = tid; e < 1024; e += 256) {    // vt rows (d), contiguous k
            int rr = e >> 3, s = e & 7;
            *(uint4*)(Vs + rr * 72 + s * 8) =
                *(const uint4*)(vt + (size_t)(d0 + rr) * N_NODES + b * NB + k0 + s * 8);
        }
        __syncthreads();
#pragma unroll
        for (int ks = 0; ks < 2; ks++) {
            short8 a = *(const short8*)(As + (w * 16 + lrow) * 72 + ks * 32 + quad * 8);
#pragma unroll
            for (int ct = 0; ct < 8; ct++) {
                short8 bfr = *(const short8*)(Vs + (ct * 16 + lrow) * 72 + ks * 32 + quad * 8);
                acc[ct] = __builtin_amdgcn_mfma_f32_16x16x32_bf16(a, bfr, acc[ct], 0, 0, 0);
            }
        }
        __syncthreads();
    }
    int mv = gmask[b];
#pragma unroll
    for (int ct = 0; ct < 8; ct++)
#pragma unroll
        for (int r = 0; r < 4; r++) {
            int node = b * NB + rt * 64 + w * 16 + quad * 4 + r;
            int d = d0 + ct * 16 + lrow;
            out[(size_t)node * MD + d] = mv ? acc[ct][r] : 0.0f;
        }
}

// ---------------- launch -----------------------------------------------------
extern "C" void kernel_launch(void* const* d_in, const int* in_sizes, int n_in,
                              void* d_out, int out_size, void* d_ws, size_t ws_size,
                              hipStream_t stream) {
    (void)in_sizes; (void)n_in; (void)out_size; (void)ws_size;

    const float* X    = (const float*)d_in[0];
    const float* pos  = (const float*)d_in[1];
    const int*   gmask= (const int*)  d_in[3];
    const float* Wq   = (const float*)d_in[4];
    const float* bq   = (const float*)d_in[5];
    const float* Wk   = (const float*)d_in[6];
    const float* bk   = (const float*)d_in[7];
    const float* Wv   = (const float*)d_in[8];
    const float* bv   = (const float*)d_in[9];
    float* out = (float*)d_out;

    char* ws = (char*)d_ws;
    float2* csp = (float2*)(ws + OFF_CS);
    u16*   wt   = (u16*)  (ws + OFF_WT);
    u16*   qrp  = (u16*)  (ws + OFF_QR);
    u16*   krp  = (u16*)  (ws + OFF_KR);
    u16*   vtp  = (u16*)  (ws + OFF_VT);
    u16*   vbfp = (u16*)  (ws + OFF_VBF);
    u16*   App  = (u16*)  (ws + OFF_AP);
    u16*   Abfp = (u16*)  (ws + OFF_ABF);

    k_trig   <<<dim3((N_NODES * 192) / 256), dim3(256), 0, stream>>>(pos, csp);
    k_wtrans <<<dim3(9, 4),                  dim3(256), 0, stream>>>(Wq, Wk, Wv, wt);
    k_qkv    <<<dim3(64, 9, 3),              dim3(256), 0, stream>>>(X, wt, bq, bk, bv,
                                                                     csp, qrp, krp, vbfp);
    k_transv <<<dim3(64, 18),                dim3(256), 0, stream>>>(vbfp, vtp);
    k_gemm1  <<<dim3(16, 16, 6),             dim3(256), 0, stream>>>(qrp, krp, App);
    k_reduceA<<<dim3(512),                   dim3(256), 0, stream>>>(App, Abfp);
    k_gemm2  <<<dim3(4, 9, 16),              dim3(256), 0, stream>>>(Abfp, vtp, gmask, out);
}